// Round 7
// baseline (331.118 us; speedup 1.0000x reference)
//
#include <hip/hip_runtime.h>

typedef __bf16 bf16x8 __attribute__((ext_vector_type(8)));
typedef float f32x16 __attribute__((ext_vector_type(16)));
typedef unsigned int uintv2 __attribute__((ext_vector_type(2)));

#define LOG2E 1.44269504088896340736f
// sched_barrier mask: SALU(0x4) | MFMA(0x8) | DS_READ(0x100) may cross;
// VALU/TRANS pinned -> bounded live ranges, but next gate's MFMA chain +
// LDS reads can overlap this gate's elementwise work.
#define FENCE() __builtin_amdgcn_sched_barrier(0x10C)

// pack two floats as bf16 pair (lo = a, hi = b)
static __device__ __forceinline__ unsigned pk2(float a, float b) {
  unsigned short ua = __builtin_bit_cast(unsigned short, (__bf16)a);
  unsigned short ub = __builtin_bit_cast(unsigned short, (__bf16)b);
  return ((unsigned)ub << 16) | (unsigned)ua;
}

static __device__ __forceinline__ f32x16 mfma_bf16(bf16x8 a, bf16x8 b, f32x16 c) {
  return __builtin_amdgcn_mfma_f32_32x32x16_bf16(a, b, c, 0, 0, 0);
}
static __device__ __forceinline__ bf16x8 frag_of(uint4 w) {
  return __builtin_bit_cast(bf16x8, w);
}
static __device__ __forceinline__ f32x16 load16(const float* p) {
  const float4 q0 = *(const float4*)(p + 0);
  const float4 q1 = *(const float4*)(p + 4);
  const float4 q2 = *(const float4*)(p + 8);
  const float4 q3 = *(const float4*)(p + 12);
  return (f32x16){q0.x, q0.y, q0.z, q0.w, q1.x, q1.y, q1.z, q1.w,
                  q2.x, q2.y, q2.z, q2.w, q3.x, q3.y, q3.z, q3.w};
}

// Build B-operand fragments for the 4 h K-steps from D-layout packed words.
static __device__ __forceinline__ void build_hfrag(const unsigned hpk[2][8], bf16x8 hfrag[4]) {
#pragma unroll
  for (int ks = 0; ks < 4; ++ks) {
    const int T = ks >> 1, s2 = ks & 1;
    uintv2 ra = __builtin_amdgcn_permlane32_swap(hpk[T][4 * s2 + 0], hpk[T][4 * s2 + 2], false, false);
    uintv2 rb = __builtin_amdgcn_permlane32_swap(hpk[T][4 * s2 + 1], hpk[T][4 * s2 + 3], false, false);
    uint4 w; w.x = ra[0]; w.y = rb[0]; w.z = ra[1]; w.w = rb[1];
    hfrag[ks] = frag_of(w);
  }
}
static __device__ __forceinline__ bf16x8 build_xfrag(const unsigned xpk[4]) {
  uintv2 ra = __builtin_amdgcn_permlane32_swap(xpk[0], xpk[2], false, false);
  uintv2 rb = __builtin_amdgcn_permlane32_swap(xpk[1], xpk[3], false, false);
  uint4 w; w.x = ra[0]; w.y = rb[0]; w.z = ra[1]; w.w = rb[1];
  return frag_of(w);
}

// Accumulate one gate's 5-K MFMA chain from LDS A-fragments.
static __device__ __forceinline__ f32x16 gate_acc(const uint4* s_frag, int m, int lane,
                                                  const bf16x8 hfrag[4], bf16x8 xfrag,
                                                  f32x16 acc) {
#pragma unroll
  for (int ks = 0; ks < 4; ++ks)
    acc = mfma_bf16(frag_of(s_frag[(m * 5 + ks) * 64 + lane]), hfrag[ks], acc);
  acc = mfma_bf16(frag_of(s_frag[(m * 5 + 4) * 64 + lane]), xfrag, acc);
  return acc;
}

// LDS frag slots: [0,40) gates (m*5+ks), [40,44) h2p, [44] se, [45,49) conf
// Gate weight rows pre-scaled: i/f/o by -log2e, g by +2*log2e, so the MFMA
// output is directly the exp2 argument.
// One 1024-thread block per CU: 16 waves share a single LDS weight copy.
// launch_bounds(1024,4): pin 4 waves/EU -> RA must stay <=128 total regs
// (64 VGPR + ~64 AGPR today) instead of spilling for ILP.
template <bool USE_WS>
__global__ __launch_bounds__(1024, 4)
void mmdec_kernel(const float* __restrict__ traj_rel,
                  const float* __restrict__ h0p, const float* __restrict__ c0p,
                  const float* __restrict__ W_ih, const float* __restrict__ W_hh,
                  const float* __restrict__ b_ih, const float* __restrict__ b_hh,
                  const float* __restrict__ W_se, const float* __restrict__ b_se,
                  const float* __restrict__ W_h2p, const float* __restrict__ b_h2p,
                  const float* __restrict__ W_conf, const float* __restrict__ b_conf,
                  float* __restrict__ out, float* __restrict__ wsP, int btot)
{
  __shared__ uint4 s_frag[49 * 64];
  __shared__ __align__(16) float s_gb[256];
  __shared__ __align__(16) float s_rb[32];
  __shared__ __align__(16) float s_xb[32];
  __shared__ __align__(16) float s_cb[32];

  const int tid  = threadIdx.x;
  const int lane = tid & 63;
  const int wid  = tid >> 6;
  const int hi   = lane >> 5;   // lane half
  const int col  = lane & 31;   // batch column within wave tile / A-row

  // ---------------- one-time LDS setup (wave 0 writes weight A-fragments) ----------------
  if (wid == 0) {
    for (int m = 0; m < 8; ++m) {
      const float gs = (m == 4 || m == 5) ? (2.0f * LOG2E) : (-LOG2E);
      for (int ks = 0; ks < 5; ++ks) {
        const int row = m * 32 + col;
        const float* p = (ks < 4) ? (W_hh + row * 64 + ks * 16 + hi * 8)
                                  : (W_ih + row * 16 + hi * 8);
        uint4 w;
        w.x = pk2(gs * p[0], gs * p[1]); w.y = pk2(gs * p[2], gs * p[3]);
        w.z = pk2(gs * p[4], gs * p[5]); w.w = pk2(gs * p[6], gs * p[7]);
        s_frag[(m * 5 + ks) * 64 + lane] = w;
      }
    }
    for (int ks = 0; ks < 4; ++ks) {
      float f[8];
      for (int e = 0; e < 8; ++e)
        f[e] = (col < 6) ? W_h2p[col * 64 + ks * 16 + hi * 8 + e] : 0.f;
      uint4 w; w.x = pk2(f[0], f[1]); w.y = pk2(f[2], f[3]);
      w.z = pk2(f[4], f[5]); w.w = pk2(f[6], f[7]);
      s_frag[(40 + ks) * 64 + lane] = w;
    }
    {
      float f[8];
      for (int e = 0; e < 8; ++e) {
        const int k = hi * 8 + e;
        f[e] = (col < 16 && k < 6) ? W_se[col * 6 + k] : 0.f;
      }
      uint4 w; w.x = pk2(f[0], f[1]); w.y = pk2(f[2], f[3]);
      w.z = pk2(f[4], f[5]); w.w = pk2(f[6], f[7]);
      s_frag[44 * 64 + lane] = w;
    }
    for (int ks = 0; ks < 4; ++ks) {
      float f[8];
      for (int e = 0; e < 8; ++e)
        f[e] = (col < 3) ? W_conf[col * 64 + ks * 16 + hi * 8 + e] : 0.f;
      uint4 w; w.x = pk2(f[0], f[1]); w.y = pk2(f[2], f[3]);
      w.z = pk2(f[4], f[5]); w.w = pk2(f[6], f[7]);
      s_frag[(45 + ks) * 64 + lane] = w;
    }
  }
  {
    const int r = tid & 15;
    if (tid < 256) {
      const int bh = tid >> 7, m = (tid >> 4) & 7;
      const float gs = (m == 4 || m == 5) ? (2.0f * LOG2E) : (-LOG2E);
      const int row = m * 32 + (r & 3) + ((r >> 2) << 3) + bh * 4;
      s_gb[tid] = gs * (b_ih[row] + b_hh[row]);
    }
    if (tid < 32) {
      const int bh = tid >> 4;
      const int row = (r & 3) + ((r >> 2) << 3) + bh * 4;
      s_rb[tid] = (row < 6)  ? b_h2p[row]  : 0.f;
      s_xb[tid] = (row < 16) ? b_se[row]   : 0.f;
      s_cb[tid] = (row < 3)  ? b_conf[row] : 0.f;
    }
  }
  __syncthreads();

  // ---------------- per-wave state init ----------------
  const int batch = (blockIdx.x * 16 + wid) * 32 + col;
  float cst[2][16];
  unsigned hpk[2][8];
  bf16x8 hfrag[4];
  bf16x8 xfrag;

  {
    float hv[2][16];
#pragma unroll
    for (int T = 0; T < 2; ++T) {
#pragma unroll
      for (int q = 0; q < 4; ++q) {
        const float4 h4 = *(const float4*)(h0p + (long)batch * 64 + T * 32 + q * 8 + hi * 4);
        const float4 c4 = *(const float4*)(c0p + (long)batch * 64 + T * 32 + q * 8 + hi * 4);
        hv[T][q * 4 + 0] = h4.x; hv[T][q * 4 + 1] = h4.y; hv[T][q * 4 + 2] = h4.z; hv[T][q * 4 + 3] = h4.w;
        cst[T][q * 4 + 0] = c4.x; cst[T][q * 4 + 1] = c4.y; cst[T][q * 4 + 2] = c4.z; cst[T][q * 4 + 3] = c4.w;
      }
    }
#pragma unroll
    for (int T = 0; T < 2; ++T)
#pragma unroll
      for (int j = 0; j < 8; ++j)
        hpk[T][j] = pk2(hv[T][2 * j], hv[T][2 * j + 1]);
    build_hfrag(hpk, hfrag);
  }
  {
    const float tx = traj_rel[(long)batch * 2 + 0];
    const float ty = traj_rel[(long)batch * 2 + 1];
    unsigned xpk[4];
#pragma unroll
    for (int j = 0; j < 4; ++j) {
      float vv[2];
#pragma unroll
      for (int u = 0; u < 2; ++u) {
        const int r = 2 * j + u;
        const int row = (r & 3) + ((r >> 2) << 3) + hi * 4;
        const float a0 = W_se[row * 6 + 0] + W_se[row * 6 + 2] + W_se[row * 6 + 4];
        const float a1 = W_se[row * 6 + 1] + W_se[row * 6 + 3] + W_se[row * 6 + 5];
        const float v = tx * a0 + ty * a1 + b_se[row];
        vv[u] = (v >= 0.f) ? v : 0.01f * v;
      }
      xpk[j] = pk2(vv[0], vv[1]);
    }
    xfrag = build_xfrag(xpk);
  }

  float* outP = out + (long)batch * 180;
  float* outC = out + (long)btot * 180 + (long)batch * 3;

  // ---------------- 30-step recurrence ----------------
#pragma unroll 1
  for (int t = 0; t < 30; ++t) {
    // Gate order g -> i -> f(+fuse) -> o.
    // Single-rcp i/f/g fuse:  R = rcp((1+ei)(1+eg)(1+ef)),
    //   c' = (c*(1+ei)(1+eg) + (eg-1)(1+ef)) * R
    // o-stage: sig(o)*tanh(c) = (ec-1)*rcp((1+eo)(1+ec)).
#pragma unroll
    for (int T = 0; T < 2; ++T) {
      f32x16 ag = gate_acc(s_frag, 4 + T, lane, hfrag, xfrag,
                           load16(s_gb + hi * 128 + (4 + T) * 16));
#pragma unroll
      for (int r = 0; r < 16; ++r)
        ag[r] = __builtin_amdgcn_exp2f(ag[r]);   // eg
      FENCE();
      f32x16 ai = gate_acc(s_frag, 0 + T, lane, hfrag, xfrag,
                           load16(s_gb + hi * 128 + (0 + T) * 16));
#pragma unroll
      for (int r = 0; r < 16; ++r)
        ai[r] = __builtin_amdgcn_exp2f(ai[r]);   // ei
      FENCE();
      {
        f32x16 af = gate_acc(s_frag, 2 + T, lane, hfrag, xfrag,
                             load16(s_gb + hi * 128 + (2 + T) * 16));
#pragma unroll
        for (int r = 0; r < 16; ++r) {
          const float ef = __builtin_amdgcn_exp2f(af[r]);
          const float a  = 1.0f + ai[r];
          const float b  = 1.0f + ag[r];
          const float f1 = 1.0f + ef;
          const float ab = a * b;
          const float R  = __builtin_amdgcn_rcpf(ab * f1);
          cst[T][r] = (cst[T][r] * ab + (ag[r] - 1.0f) * f1) * R;
        }
      }
      FENCE();
      {
        f32x16 ao = gate_acc(s_frag, 6 + T, lane, hfrag, xfrag,
                             load16(s_gb + hi * 128 + (6 + T) * 16));
#pragma unroll
        for (int j = 0; j < 8; ++j) {
          float hn[2];
#pragma unroll
          for (int u = 0; u < 2; ++u) {
            const int r = 2 * j + u;
            const float eo = __builtin_amdgcn_exp2f(ao[r]);
            const float ec = __builtin_amdgcn_exp2f((2.0f * LOG2E) * cst[T][r]);
            const float d  = __builtin_amdgcn_rcpf((1.0f + eo) * (1.0f + ec));
            hn[u] = (ec - 1.0f) * d;
          }
          hpk[T][j] = pk2(hn[0], hn[1]);
        }
      }
      FENCE();
    }
    build_hfrag(hpk, hfrag);

    // rel = h @ W_h2p^T + b_h2p (rows 0-5 of rel^T tile)
    f32x16 racc = load16(s_rb + hi * 16);
#pragma unroll
    for (int ks = 0; ks < 4; ++ks)
      racc = mfma_bf16(frag_of(s_frag[(40 + ks) * 64 + lane]), hfrag[ks], racc);

    // pred store
    if (USE_WS) {
      // coalesced staging layout matching final flat order: ws[(s*30+t)*btot + batch][2]
      if (hi == 0) {
        float2 v0; v0.x = racc[0]; v0.y = racc[1];
        float2 v1; v1.x = racc[2]; v1.y = racc[3];
        *(float2*)(wsP + ((long)(0 * 30 + t) * btot + batch) * 2) = v0;
        *(float2*)(wsP + ((long)(1 * 30 + t) * btot + batch) * 2) = v1;
      } else {
        float2 v2; v2.x = racc[0]; v2.y = racc[1];
        *(float2*)(wsP + ((long)(2 * 30 + t) * btot + batch) * 2) = v2;
      }
    } else {
      if (hi == 0) {
        float2 v0; v0.x = racc[0]; v0.y = racc[1];
        float2 v1; v1.x = racc[2]; v1.y = racc[3];
        *(float2*)(outP + t * 2)       = v0;
        *(float2*)(outP + 60 + t * 2)  = v1;
      } else {
        float2 v2; v2.x = racc[0]; v2.y = racc[1];
        *(float2*)(outP + 120 + t * 2) = v2;
      }
    }

    // x = leaky(rel @ W_se^T + b_se)
    {
      const unsigned qw = pk2(racc[0], racc[1]);
      const unsigned pw = pk2(racc[2], racc[3]); // upper lanes: rows 6,7 == 0
      uintv2 sw = __builtin_amdgcn_permlane32_swap(qw, 0u, false, false);
      uint4 rw; rw.x = sw[0]; rw.y = pw; rw.z = sw[1]; rw.w = 0u;
      f32x16 xacc = load16(s_xb + hi * 16);
      xacc = mfma_bf16(frag_of(s_frag[44 * 64 + lane]), frag_of(rw), xacc);
      unsigned xpk[4];
#pragma unroll
      for (int j = 0; j < 4; ++j) {
        float v0 = xacc[2 * j], v1 = xacc[2 * j + 1];
        v0 = (v0 >= 0.f) ? v0 : 0.01f * v0;
        v1 = (v1 >= 0.f) ? v1 : 0.01f * v1;
        xpk[j] = pk2(v0, v1);
      }
      xfrag = build_xfrag(xpk);
    }
  }

  // ---------------- conf = softmax(h @ W_conf^T + b_conf) ----------------
  {
    f32x16 cacc = load16(s_cb + hi * 16);
#pragma unroll
    for (int ks = 0; ks < 4; ++ks)
      cacc = mfma_bf16(frag_of(s_frag[(45 + ks) * 64 + lane]), hfrag[ks], cacc);
    if (hi == 0) {
      const float a = cacc[0], b = cacc[1], c = cacc[2];
      const float mx = fmaxf(a, fmaxf(b, c));
      const float e0 = __builtin_amdgcn_exp2f(LOG2E * (a - mx));
      const float e1 = __builtin_amdgcn_exp2f(LOG2E * (b - mx));
      const float e2 = __builtin_amdgcn_exp2f(LOG2E * (c - mx));
      const float rs = __builtin_amdgcn_rcpf(e0 + e1 + e2);
      outC[0] = e0 * rs; outC[1] = e1 * rs; outC[2] = e2 * rs;
    }
  }
}

// Copy ws[(s*30+t)][b][2] -> out[b][s*60+t*2+c]; LDS flat order == output flat order.
__global__ __launch_bounds__(256)
void transpose_pred(const float* __restrict__ ws, float* __restrict__ out, int btot)
{
  __shared__ float s_t[64][188];   // 188 pad: 752B row stride (16B-aligned, bank-spread)
  const int tid = threadIdx.x;
  const long b0 = (long)blockIdx.x * 64;

  // load: 90 (s,t) chunks x 64 batches of float2, coalesced on batch
#pragma unroll 1
  for (int i = 0; i < 23; ++i) {
    const int idx = tid + i * 256;
    if (idx < 5760) {
      const int e = idx >> 6, bb = idx & 63;
      const float2 v = *(const float2*)(ws + ((long)e * btot + b0 + bb) * 2);
      *(float2*)&s_t[bb][e * 2] = v;
    }
  }
  __syncthreads();

  // store: per batch 180 contiguous floats (720B), float4 granularity
#pragma unroll 1
  for (int i = 0; i < 12; ++i) {
    const int idx = tid + i * 256;
    if (idx < 2880) {
      const int b = idx / 45, k = idx % 45;
      *(float4*)(out + (b0 + b) * 180 + k * 4) = *(const float4*)&s_t[b][k * 4];
    }
  }
}

extern "C" void kernel_launch(void* const* d_in, const int* in_sizes, int n_in,
                              void* d_out, int out_size, void* d_ws, size_t ws_size,
                              hipStream_t stream) {
  const float* traj_rel = (const float*)d_in[1];
  const float* h0p    = (const float*)d_in[2];
  const float* c0p    = (const float*)d_in[3];
  const float* W_ih   = (const float*)d_in[4];
  const float* W_hh   = (const float*)d_in[5];
  const float* b_ih   = (const float*)d_in[6];
  const float* b_hh   = (const float*)d_in[7];
  const float* W_se   = (const float*)d_in[8];
  const float* b_se   = (const float*)d_in[9];
  const float* W_h2p  = (const float*)d_in[10];
  const float* b_h2p  = (const float*)d_in[11];
  const float* W_conf = (const float*)d_in[12];
  const float* b_conf = (const float*)d_in[13];

  const int btot = in_sizes[1] / 2;        // 131072
  const int grid = btot / 512;             // 16 waves/block * 32 batch/wave = 256 blocks

  const size_t ws_need = (size_t)90 * (size_t)btot * 2 * sizeof(float);
  if (ws_size >= ws_need) {
    mmdec_kernel<true><<<grid, 1024, 0, stream>>>(traj_rel, h0p, c0p, W_ih, W_hh, b_ih, b_hh,
                                                  W_se, b_se, W_h2p, b_h2p, W_conf, b_conf,
                                                  (float*)d_out, (float*)d_ws, btot);
    transpose_pred<<<btot / 64, 256, 0, stream>>>((const float*)d_ws, (float*)d_out, btot);
  } else {
    mmdec_kernel<false><<<grid, 1024, 0, stream>>>(traj_rel, h0p, c0p, W_ih, W_hh, b_ih, b_hh,
                                                   W_se, b_se, W_h2p, b_h2p, W_conf, b_conf,
                                                   (float*)d_out, nullptr, btot);
  }
}

// Round 9
// 325.301 us; speedup vs baseline: 1.0179x; 1.0179x over previous
//
#include <hip/hip_runtime.h>

typedef __bf16 bf16x8 __attribute__((ext_vector_type(8)));
typedef float f32x16 __attribute__((ext_vector_type(16)));
typedef float f32x2 __attribute__((ext_vector_type(2)));
typedef unsigned int uintv2 __attribute__((ext_vector_type(2)));

#define LOG2E 1.44269504088896340736f
// sched_barrier mask: SALU(0x4) | MFMA(0x8) | DS_READ(0x100) may cross.
#define FENCE() __builtin_amdgcn_sched_barrier(0x10C)

// pack two floats as bf16 pair (lo = a, hi = b)
static __device__ __forceinline__ unsigned pk2(float a, float b) {
  unsigned short ua = __builtin_bit_cast(unsigned short, (__bf16)a);
  unsigned short ub = __builtin_bit_cast(unsigned short, (__bf16)b);
  return ((unsigned)ub << 16) | (unsigned)ua;
}

static __device__ __forceinline__ f32x16 mfma_bf16(bf16x8 a, bf16x8 b, f32x16 c) {
  return __builtin_amdgcn_mfma_f32_32x32x16_bf16(a, b, c, 0, 0, 0);
}
static __device__ __forceinline__ bf16x8 frag_of(uint4 w) {
  return __builtin_bit_cast(bf16x8, w);
}
static __device__ __forceinline__ f32x16 load16(const float* p) {
  const float4 q0 = *(const float4*)(p + 0);
  const float4 q1 = *(const float4*)(p + 4);
  const float4 q2 = *(const float4*)(p + 8);
  const float4 q3 = *(const float4*)(p + 12);
  return (f32x16){q0.x, q0.y, q0.z, q0.w, q1.x, q1.y, q1.z, q1.w,
                  q2.x, q2.y, q2.z, q2.w, q3.x, q3.y, q3.z, q3.w};
}

// Build B-operand fragments for the 4 h K-steps from D-layout packed words.
static __device__ __forceinline__ void build_hfrag(const unsigned hpk[2][8], bf16x8 hfrag[4]) {
#pragma unroll
  for (int ks = 0; ks < 4; ++ks) {
    const int T = ks >> 1, s2 = ks & 1;
    uintv2 ra = __builtin_amdgcn_permlane32_swap(hpk[T][4 * s2 + 0], hpk[T][4 * s2 + 2], false, false);
    uintv2 rb = __builtin_amdgcn_permlane32_swap(hpk[T][4 * s2 + 1], hpk[T][4 * s2 + 3], false, false);
    uint4 w; w.x = ra[0]; w.y = rb[0]; w.z = ra[1]; w.w = rb[1];
    hfrag[ks] = frag_of(w);
  }
}
static __device__ __forceinline__ bf16x8 build_xfrag(const unsigned xpk[4]) {
  uintv2 ra = __builtin_amdgcn_permlane32_swap(xpk[0], xpk[2], false, false);
  uintv2 rb = __builtin_amdgcn_permlane32_swap(xpk[1], xpk[3], false, false);
  uint4 w; w.x = ra[0]; w.y = rb[0]; w.z = ra[1]; w.w = rb[1];
  return frag_of(w);
}

// Accumulate one gate's 5-K MFMA chain from LDS A-fragments.
static __device__ __forceinline__ f32x16 gate_acc(const uint4* s_frag, int m, int lane,
                                                  const bf16x8 hfrag[4], bf16x8 xfrag,
                                                  f32x16 acc) {
#pragma unroll
  for (int ks = 0; ks < 4; ++ks)
    acc = mfma_bf16(frag_of(s_frag[(m * 5 + ks) * 64 + lane]), hfrag[ks], acc);
  acc = mfma_bf16(frag_of(s_frag[(m * 5 + 4) * 64 + lane]), xfrag, acc);
  return acc;
}

// LDS frag slots: [0,40) gates (m*5+ks), [40,44) h2p, [44] se, [45,49) conf
// Gate weight rows pre-scaled: i/f/o by -log2e, g by +2*log2e, so the MFMA
// output is directly the exp2 argument (hardware v_exp_f32).
template <bool USE_WS>
__global__ __launch_bounds__(1024, 4)
void mmdec_kernel(const float* __restrict__ traj_rel,
                  const float* __restrict__ h0p, const float* __restrict__ c0p,
                  const float* __restrict__ W_ih, const float* __restrict__ W_hh,
                  const float* __restrict__ b_ih, const float* __restrict__ b_hh,
                  const float* __restrict__ W_se, const float* __restrict__ b_se,
                  const float* __restrict__ W_h2p, const float* __restrict__ b_h2p,
                  const float* __restrict__ W_conf, const float* __restrict__ b_conf,
                  float* __restrict__ out, float* __restrict__ wsP, int btot)
{
  __shared__ uint4 s_frag[49 * 64];
  __shared__ __align__(16) float s_gb[256];
  __shared__ __align__(16) float s_rb[32];
  __shared__ __align__(16) float s_xb[32];
  __shared__ __align__(16) float s_cb[32];

  const int tid  = threadIdx.x;
  const int lane = tid & 63;
  const int wid  = tid >> 6;
  const int hi   = lane >> 5;   // lane half
  const int col  = lane & 31;   // batch column within wave tile / A-row

  // ---------------- one-time LDS setup (wave 0 writes weight A-fragments) ----------------
  if (wid == 0) {
    for (int m = 0; m < 8; ++m) {
      const float gs = (m == 4 || m == 5) ? (2.0f * LOG2E) : (-LOG2E);
      for (int ks = 0; ks < 5; ++ks) {
        const int row = m * 32 + col;
        const float* p = (ks < 4) ? (W_hh + row * 64 + ks * 16 + hi * 8)
                                  : (W_ih + row * 16 + hi * 8);
        uint4 w;
        w.x = pk2(gs * p[0], gs * p[1]); w.y = pk2(gs * p[2], gs * p[3]);
        w.z = pk2(gs * p[4], gs * p[5]); w.w = pk2(gs * p[6], gs * p[7]);
        s_frag[(m * 5 + ks) * 64 + lane] = w;
      }
    }
    for (int ks = 0; ks < 4; ++ks) {
      float f[8];
      for (int e = 0; e < 8; ++e)
        f[e] = (col < 6) ? W_h2p[col * 64 + ks * 16 + hi * 8 + e] : 0.f;
      uint4 w; w.x = pk2(f[0], f[1]); w.y = pk2(f[2], f[3]);
      w.z = pk2(f[4], f[5]); w.w = pk2(f[6], f[7]);
      s_frag[(40 + ks) * 64 + lane] = w;
    }
    {
      float f[8];
      for (int e = 0; e < 8; ++e) {
        const int k = hi * 8 + e;
        f[e] = (col < 16 && k < 6) ? W_se[col * 6 + k] : 0.f;
      }
      uint4 w; w.x = pk2(f[0], f[1]); w.y = pk2(f[2], f[3]);
      w.z = pk2(f[4], f[5]); w.w = pk2(f[6], f[7]);
      s_frag[44 * 64 + lane] = w;
    }
    for (int ks = 0; ks < 4; ++ks) {
      float f[8];
      for (int e = 0; e < 8; ++e)
        f[e] = (col < 3) ? W_conf[col * 64 + ks * 16 + hi * 8 + e] : 0.f;
      uint4 w; w.x = pk2(f[0], f[1]); w.y = pk2(f[2], f[3]);
      w.z = pk2(f[4], f[5]); w.w = pk2(f[6], f[7]);
      s_frag[(45 + ks) * 64 + lane] = w;
    }
  }
  {
    const int r = tid & 15;
    if (tid < 256) {
      const int bh = tid >> 7, m = (tid >> 4) & 7;
      const float gs = (m == 4 || m == 5) ? (2.0f * LOG2E) : (-LOG2E);
      const int row = m * 32 + (r & 3) + ((r >> 2) << 3) + bh * 4;
      s_gb[tid] = gs * (b_ih[row] + b_hh[row]);
    }
    if (tid < 32) {
      const int bh = tid >> 4;
      const int row = (r & 3) + ((r >> 2) << 3) + bh * 4;
      s_rb[tid] = (row < 6)  ? b_h2p[row]  : 0.f;
      s_xb[tid] = (row < 16) ? b_se[row]   : 0.f;
      s_cb[tid] = (row < 3)  ? b_conf[row] : 0.f;
    }
  }
  __syncthreads();

  // ---------------- per-wave state init ----------------
  const int batch = (blockIdx.x * 16 + wid) * 32 + col;
  float cst[2][16];
  unsigned hpk[2][8];
  bf16x8 hfrag[4];
  bf16x8 xfrag;

  {
    float hv[2][16];
#pragma unroll
    for (int T = 0; T < 2; ++T) {
#pragma unroll
      for (int q = 0; q < 4; ++q) {
        const float4 h4 = *(const float4*)(h0p + (long)batch * 64 + T * 32 + q * 8 + hi * 4);
        const float4 c4 = *(const float4*)(c0p + (long)batch * 64 + T * 32 + q * 8 + hi * 4);
        hv[T][q * 4 + 0] = h4.x; hv[T][q * 4 + 1] = h4.y; hv[T][q * 4 + 2] = h4.z; hv[T][q * 4 + 3] = h4.w;
        cst[T][q * 4 + 0] = c4.x; cst[T][q * 4 + 1] = c4.y; cst[T][q * 4 + 2] = c4.z; cst[T][q * 4 + 3] = c4.w;
      }
    }
#pragma unroll
    for (int T = 0; T < 2; ++T)
#pragma unroll
      for (int j = 0; j < 8; ++j)
        hpk[T][j] = pk2(hv[T][2 * j], hv[T][2 * j + 1]);
    build_hfrag(hpk, hfrag);
  }
  {
    const float tx = traj_rel[(long)batch * 2 + 0];
    const float ty = traj_rel[(long)batch * 2 + 1];
    unsigned xpk[4];
#pragma unroll
    for (int j = 0; j < 4; ++j) {
      float vv[2];
#pragma unroll
      for (int u = 0; u < 2; ++u) {
        const int r = 2 * j + u;
        const int row = (r & 3) + ((r >> 2) << 3) + hi * 4;
        const float a0 = W_se[row * 6 + 0] + W_se[row * 6 + 2] + W_se[row * 6 + 4];
        const float a1 = W_se[row * 6 + 1] + W_se[row * 6 + 3] + W_se[row * 6 + 5];
        const float v = tx * a0 + ty * a1 + b_se[row];
        vv[u] = (v >= 0.f) ? v : 0.01f * v;
      }
      xpk[j] = pk2(vv[0], vv[1]);
    }
    xfrag = build_xfrag(xpk);
  }

  float* outP = out + (long)batch * 180;
  float* outC = out + (long)btot * 180 + (long)batch * 3;

  // ---------------- 30-step recurrence ----------------
#pragma unroll 1
  for (int t = 0; t < 30; ++t) {
    // Gate order g -> i -> f(+fuse) -> o; hardware exp2, PAIRED rcp:
    //   c' = (c*(1+ei)(1+eg) + (eg-1)(1+ef)) * rcp((1+ei)(1+eg)(1+ef))
    //   h  = (ec-1) * rcp((1+eo)(1+ec)),  ec = 2^(2*log2e*c')
    // One rcp per element PAIR: RP = rcp(D0*D1); x0*=RP*D1, x1*=RP*D0.
    // f32x2 algebra so the backend can emit v_pk_*_f32.
#pragma unroll
    for (int T = 0; T < 2; ++T) {
      f32x16 ag = gate_acc(s_frag, 4 + T, lane, hfrag, xfrag,
                           load16(s_gb + hi * 128 + (4 + T) * 16));
#pragma unroll
      for (int r = 0; r < 16; ++r)
        ag[r] = __builtin_amdgcn_exp2f(ag[r]);   // eg
      FENCE();
      f32x16 ai = gate_acc(s_frag, 0 + T, lane, hfrag, xfrag,
                           load16(s_gb + hi * 128 + (0 + T) * 16));
#pragma unroll
      for (int r = 0; r < 16; ++r)
        ai[r] = __builtin_amdgcn_exp2f(ai[r]);   // ei
      FENCE();
      {
        f32x16 af = gate_acc(s_frag, 2 + T, lane, hfrag, xfrag,
                             load16(s_gb + hi * 128 + (2 + T) * 16));
#pragma unroll
        for (int j = 0; j < 8; ++j) {
          const int r0 = 2 * j, r1 = 2 * j + 1;
          f32x2 F; F[0] = 1.0f + __builtin_amdgcn_exp2f(af[r0]);
                   F[1] = 1.0f + __builtin_amdgcn_exp2f(af[r1]);
          f32x2 A; A[0] = 1.0f + ai[r0]; A[1] = 1.0f + ai[r1];
          f32x2 B; B[0] = 1.0f + ag[r0]; B[1] = 1.0f + ag[r1];
          f32x2 G; G[0] = ag[r0] - 1.0f; G[1] = ag[r1] - 1.0f;
          f32x2 C; C[0] = cst[T][r0];    C[1] = cst[T][r1];
          const f32x2 AB = A * B;
          const f32x2 D  = AB * F;
          const f32x2 N  = C * AB + G * F;
          const float RP = __builtin_amdgcn_rcpf(D[0] * D[1]);
          cst[T][r0] = N[0] * (RP * D[1]);
          cst[T][r1] = N[1] * (RP * D[0]);
        }
      }
      FENCE();
      {
        f32x16 ao = gate_acc(s_frag, 6 + T, lane, hfrag, xfrag,
                             load16(s_gb + hi * 128 + (6 + T) * 16));
#pragma unroll
        for (int j = 0; j < 8; ++j) {
          const int r0 = 2 * j, r1 = 2 * j + 1;
          f32x2 EC; EC[0] = __builtin_amdgcn_exp2f((2.0f * LOG2E) * cst[T][r0]);
                    EC[1] = __builtin_amdgcn_exp2f((2.0f * LOG2E) * cst[T][r1]);
          f32x2 O; O[0] = 1.0f + __builtin_amdgcn_exp2f(ao[r0]);
                   O[1] = 1.0f + __builtin_amdgcn_exp2f(ao[r1]);
          const f32x2 E1 = 1.0f + EC;
          const f32x2 D  = O * E1;
          const float RP = __builtin_amdgcn_rcpf(D[0] * D[1]);
          const float h0v = (EC[0] - 1.0f) * (RP * D[1]);
          const float h1v = (EC[1] - 1.0f) * (RP * D[0]);
          hpk[T][j] = pk2(h0v, h1v);
        }
      }
      FENCE();
    }
    build_hfrag(hpk, hfrag);

    // rel = h @ W_h2p^T + b_h2p (rows 0-5 of rel^T tile)
    f32x16 racc = load16(s_rb + hi * 16);
#pragma unroll
    for (int ks = 0; ks < 4; ++ks)
      racc = mfma_bf16(frag_of(s_frag[(40 + ks) * 64 + lane]), hfrag[ks], racc);

    // pred store
    if (USE_WS) {
      // coalesced staging layout matching final flat order: ws[(s*30+t)*btot + batch][2]
      if (hi == 0) {
        float2 v0; v0.x = racc[0]; v0.y = racc[1];
        float2 v1; v1.x = racc[2]; v1.y = racc[3];
        *(float2*)(wsP + ((long)(0 * 30 + t) * btot + batch) * 2) = v0;
        *(float2*)(wsP + ((long)(1 * 30 + t) * btot + batch) * 2) = v1;
      } else {
        float2 v2; v2.x = racc[0]; v2.y = racc[1];
        *(float2*)(wsP + ((long)(2 * 30 + t) * btot + batch) * 2) = v2;
      }
    } else {
      if (hi == 0) {
        float2 v0; v0.x = racc[0]; v0.y = racc[1];
        float2 v1; v1.x = racc[2]; v1.y = racc[3];
        *(float2*)(outP + t * 2)       = v0;
        *(float2*)(outP + 60 + t * 2)  = v1;
      } else {
        float2 v2; v2.x = racc[0]; v2.y = racc[1];
        *(float2*)(outP + 120 + t * 2) = v2;
      }
    }

    // x = leaky(rel @ W_se^T + b_se)
    {
      const unsigned qw = pk2(racc[0], racc[1]);
      const unsigned pw = pk2(racc[2], racc[3]); // upper lanes: rows 6,7 == 0
      uintv2 sw = __builtin_amdgcn_permlane32_swap(qw, 0u, false, false);
      uint4 rw; rw.x = sw[0]; rw.y = pw; rw.z = sw[1]; rw.w = 0u;
      f32x16 xacc = load16(s_xb + hi * 16);
      xacc = mfma_bf16(frag_of(s_frag[44 * 64 + lane]), frag_of(rw), xacc);
      unsigned xpk[4];
#pragma unroll
      for (int j = 0; j < 4; ++j) {
        float v0 = xacc[2 * j], v1 = xacc[2 * j + 1];
        v0 = (v0 >= 0.f) ? v0 : 0.01f * v0;
        v1 = (v1 >= 0.f) ? v1 : 0.01f * v1;
        xpk[j] = pk2(v0, v1);
      }
      xfrag = build_xfrag(xpk);
    }
  }

  // ---------------- conf = softmax(h @ W_conf^T + b_conf) ----------------
  {
    f32x16 cacc = load16(s_cb + hi * 16);
#pragma unroll
    for (int ks = 0; ks < 4; ++ks)
      cacc = mfma_bf16(frag_of(s_frag[(45 + ks) * 64 + lane]), hfrag[ks], cacc);
    if (hi == 0) {
      const float a = cacc[0], b = cacc[1], c = cacc[2];
      const float mx = fmaxf(a, fmaxf(b, c));
      const float e0 = __builtin_amdgcn_exp2f(LOG2E * (a - mx));
      const float e1 = __builtin_amdgcn_exp2f(LOG2E * (b - mx));
      const float e2 = __builtin_amdgcn_exp2f(LOG2E * (c - mx));
      const float rs = __builtin_amdgcn_rcpf(e0 + e1 + e2);
      outC[0] = e0 * rs; outC[1] = e1 * rs; outC[2] = e2 * rs;
    }
  }
}

// Copy ws[(s*30+t)][b][2] -> out[b][s*60+t*2+c]; LDS flat order == output flat order.
__global__ __launch_bounds__(256)
void transpose_pred(const float* __restrict__ ws, float* __restrict__ out, int btot)
{
  __shared__ float s_t[64][188];   // 188 pad: 752B row stride (16B-aligned, bank-spread)
  const int tid = threadIdx.x;
  const long b0 = (long)blockIdx.x * 64;

  // load: 90 (s,t) chunks x 64 batches of float2, coalesced on batch
#pragma unroll 1
  for (int i = 0; i < 23; ++i) {
    const int idx = tid + i * 256;
    if (idx < 5760) {
      const int e = idx >> 6, bb = idx & 63;
      const float2 v = *(const float2*)(ws + ((long)e * btot + b0 + bb) * 2);
      *(float2*)&s_t[bb][e * 2] = v;
    }
  }
  __syncthreads();

  // store: per batch 180 contiguous floats (720B), float4 granularity
#pragma unroll 1
  for (int i = 0; i < 12; ++i) {
    const int idx = tid + i * 256;
    if (idx < 2880) {
      const int b = idx / 45, k = idx % 45;
      *(float4*)(out + (b0 + b) * 180 + k * 4) = *(const float4*)&s_t[b][k * 4];
    }
  }
}

extern "C" void kernel_launch(void* const* d_in, const int* in_sizes, int n_in,
                              void* d_out, int out_size, void* d_ws, size_t ws_size,
                              hipStream_t stream) {
  const float* traj_rel = (const float*)d_in[1];
  const float* h0p    = (const float*)d_in[2];
  const float* c0p    = (const float*)d_in[3];
  const float* W_ih   = (const float*)d_in[4];
  const float* W_hh   = (const float*)d_in[5];
  const float* b_ih   = (const float*)d_in[6];
  const float* b_hh   = (const float*)d_in[7];
  const float* W_se   = (const float*)d_in[8];
  const float* b_se   = (const float*)d_in[9];
  const float* W_h2p  = (const float*)d_in[10];
  const float* b_h2p  = (const float*)d_in[11];
  const float* W_conf = (const float*)d_in[12];
  const float* b_conf = (const float*)d_in[13];

  const int btot = in_sizes[1] / 2;        // 131072
  const int grid = btot / 512;             // 16 waves/block * 32 batch/wave = 256 blocks

  const size_t ws_need = (size_t)90 * (size_t)btot * 2 * sizeof(float);
  if (ws_size >= ws_need) {
    mmdec_kernel<true><<<grid, 1024, 0, stream>>>(traj_rel, h0p, c0p, W_ih, W_hh, b_ih, b_hh,
                                                  W_se, b_se, W_h2p, b_h2p, W_conf, b_conf,
                                                  (float*)d_out, (float*)d_ws, btot);
    transpose_pred<<<btot / 64, 256, 0, stream>>>((const float*)d_ws, (float*)d_out, btot);
  } else {
    mmdec_kernel<false><<<grid, 1024, 0, stream>>>(traj_rel, h0p, c0p, W_ih, W_hh, b_ih, b_hh,
                                                   W_se, b_se, W_h2p, b_h2p, W_conf, b_conf,
                                                   (float*)d_out, nullptr, btot);
  }
}

// Round 10
// 316.868 us; speedup vs baseline: 1.0450x; 1.0266x over previous
//
#include <hip/hip_runtime.h>

typedef __bf16 bf16x8 __attribute__((ext_vector_type(8)));
typedef float f32x16 __attribute__((ext_vector_type(16)));
typedef float f32x2 __attribute__((ext_vector_type(2)));
typedef unsigned int uintv2 __attribute__((ext_vector_type(2)));

#define LOG2E 1.44269504088896340736f
// sched_barrier mask: SALU(0x4) | MFMA(0x8) | DS_READ(0x100) may cross.
#define FENCE() __builtin_amdgcn_sched_barrier(0x10C)

// pack two floats as bf16 pair (lo = a, hi = b)
static __device__ __forceinline__ unsigned pk2(float a, float b) {
  unsigned short ua = __builtin_bit_cast(unsigned short, (__bf16)a);
  unsigned short ub = __builtin_bit_cast(unsigned short, (__bf16)b);
  return ((unsigned)ub << 16) | (unsigned)ua;
}

static __device__ __forceinline__ f32x16 mfma_bf16(bf16x8 a, bf16x8 b, f32x16 c) {
  return __builtin_amdgcn_mfma_f32_32x32x16_bf16(a, b, c, 0, 0, 0);
}
static __device__ __forceinline__ bf16x8 frag_of(uint4 w) {
  return __builtin_bit_cast(bf16x8, w);
}
static __device__ __forceinline__ f32x16 load16(const float* p) {
  const float4 q0 = *(const float4*)(p + 0);
  const float4 q1 = *(const float4*)(p + 4);
  const float4 q2 = *(const float4*)(p + 8);
  const float4 q3 = *(const float4*)(p + 12);
  return (f32x16){q0.x, q0.y, q0.z, q0.w, q1.x, q1.y, q1.z, q1.w,
                  q2.x, q2.y, q2.z, q2.w, q3.x, q3.y, q3.z, q3.w};
}

// Build B-operand fragments for the 4 h K-steps from D-layout packed words.
static __device__ __forceinline__ void build_hfrag(const unsigned hpk[2][8], bf16x8 hfrag[4]) {
#pragma unroll
  for (int ks = 0; ks < 4; ++ks) {
    const int T = ks >> 1, s2 = ks & 1;
    uintv2 ra = __builtin_amdgcn_permlane32_swap(hpk[T][4 * s2 + 0], hpk[T][4 * s2 + 2], false, false);
    uintv2 rb = __builtin_amdgcn_permlane32_swap(hpk[T][4 * s2 + 1], hpk[T][4 * s2 + 3], false, false);
    uint4 w; w.x = ra[0]; w.y = rb[0]; w.z = ra[1]; w.w = rb[1];
    hfrag[ks] = frag_of(w);
  }
}
static __device__ __forceinline__ bf16x8 build_xfrag(const unsigned xpk[4]) {
  uintv2 ra = __builtin_amdgcn_permlane32_swap(xpk[0], xpk[2], false, false);
  uintv2 rb = __builtin_amdgcn_permlane32_swap(xpk[1], xpk[3], false, false);
  uint4 w; w.x = ra[0]; w.y = rb[0]; w.z = ra[1]; w.w = rb[1];
  return frag_of(w);
}

// Accumulate one gate's 5-K MFMA chain from LDS A-fragments.
static __device__ __forceinline__ f32x16 gate_acc(const uint4* s_frag, int m, int lane,
                                                  const bf16x8 hfrag[4], bf16x8 xfrag,
                                                  f32x16 acc) {
#pragma unroll
  for (int ks = 0; ks < 4; ++ks)
    acc = mfma_bf16(frag_of(s_frag[(m * 5 + ks) * 64 + lane]), hfrag[ks], acc);
  acc = mfma_bf16(frag_of(s_frag[(m * 5 + 4) * 64 + lane]), xfrag, acc);
  return acc;
}

// LDS frag slots: [0,40) gates (m*5+ks), [40,44) h2p, [44] se, [45,49) conf
// Gate weight rows pre-scaled: i/f/o by -log2e, g by +2*log2e, so the MFMA
// output is directly the exp2 argument (hardware v_exp_f32).
template <bool USE_WS>
__global__ __launch_bounds__(1024, 4)
void mmdec_kernel(const float* __restrict__ traj_rel,
                  const float* __restrict__ h0p, const float* __restrict__ c0p,
                  const float* __restrict__ W_ih, const float* __restrict__ W_hh,
                  const float* __restrict__ b_ih, const float* __restrict__ b_hh,
                  const float* __restrict__ W_se, const float* __restrict__ b_se,
                  const float* __restrict__ W_h2p, const float* __restrict__ b_h2p,
                  const float* __restrict__ W_conf, const float* __restrict__ b_conf,
                  float* __restrict__ out, float* __restrict__ wsP, int btot)
{
  __shared__ uint4 s_frag[49 * 64];
  __shared__ __align__(16) float s_gb[256];
  __shared__ __align__(16) float s_rb[32];
  __shared__ __align__(16) float s_xb[32];
  __shared__ __align__(16) float s_cb[32];

  const int tid  = threadIdx.x;
  const int lane = tid & 63;
  const int wid  = tid >> 6;
  const int hi   = lane >> 5;   // lane half
  const int col  = lane & 31;   // batch column within wave tile / A-row

  // ---------------- one-time LDS setup (wave 0 writes weight A-fragments) ----------------
  if (wid == 0) {
    for (int m = 0; m < 8; ++m) {
      const float gs = (m == 4 || m == 5) ? (2.0f * LOG2E) : (-LOG2E);
      for (int ks = 0; ks < 5; ++ks) {
        const int row = m * 32 + col;
        const float* p = (ks < 4) ? (W_hh + row * 64 + ks * 16 + hi * 8)
                                  : (W_ih + row * 16 + hi * 8);
        uint4 w;
        w.x = pk2(gs * p[0], gs * p[1]); w.y = pk2(gs * p[2], gs * p[3]);
        w.z = pk2(gs * p[4], gs * p[5]); w.w = pk2(gs * p[6], gs * p[7]);
        s_frag[(m * 5 + ks) * 64 + lane] = w;
      }
    }
    for (int ks = 0; ks < 4; ++ks) {
      float f[8];
      for (int e = 0; e < 8; ++e)
        f[e] = (col < 6) ? W_h2p[col * 64 + ks * 16 + hi * 8 + e] : 0.f;
      uint4 w; w.x = pk2(f[0], f[1]); w.y = pk2(f[2], f[3]);
      w.z = pk2(f[4], f[5]); w.w = pk2(f[6], f[7]);
      s_frag[(40 + ks) * 64 + lane] = w;
    }
    {
      float f[8];
      for (int e = 0; e < 8; ++e) {
        const int k = hi * 8 + e;
        f[e] = (col < 16 && k < 6) ? W_se[col * 6 + k] : 0.f;
      }
      uint4 w; w.x = pk2(f[0], f[1]); w.y = pk2(f[2], f[3]);
      w.z = pk2(f[4], f[5]); w.w = pk2(f[6], f[7]);
      s_frag[44 * 64 + lane] = w;
    }
    for (int ks = 0; ks < 4; ++ks) {
      float f[8];
      for (int e = 0; e < 8; ++e)
        f[e] = (col < 3) ? W_conf[col * 64 + ks * 16 + hi * 8 + e] : 0.f;
      uint4 w; w.x = pk2(f[0], f[1]); w.y = pk2(f[2], f[3]);
      w.z = pk2(f[4], f[5]); w.w = pk2(f[6], f[7]);
      s_frag[(45 + ks) * 64 + lane] = w;
    }
  }
  {
    const int r = tid & 15;
    if (tid < 256) {
      const int bh = tid >> 7, m = (tid >> 4) & 7;
      const float gs = (m == 4 || m == 5) ? (2.0f * LOG2E) : (-LOG2E);
      const int row = m * 32 + (r & 3) + ((r >> 2) << 3) + bh * 4;
      s_gb[tid] = gs * (b_ih[row] + b_hh[row]);
    }
    if (tid < 32) {
      const int bh = tid >> 4;
      const int row = (r & 3) + ((r >> 2) << 3) + bh * 4;
      s_rb[tid] = (row < 6)  ? b_h2p[row]  : 0.f;
      s_xb[tid] = (row < 16) ? b_se[row]   : 0.f;
      s_cb[tid] = (row < 3)  ? b_conf[row] : 0.f;
    }
  }
  __syncthreads();

  // ---------------- per-wave state init ----------------
  const int batch = (blockIdx.x * 16 + wid) * 32 + col;
  float cst[2][16];
  unsigned hpk[2][8];
  bf16x8 hfrag[4];
  bf16x8 xfrag;

  {
    float hv[2][16];
#pragma unroll
    for (int T = 0; T < 2; ++T) {
#pragma unroll
      for (int q = 0; q < 4; ++q) {
        const float4 h4 = *(const float4*)(h0p + (long)batch * 64 + T * 32 + q * 8 + hi * 4);
        const float4 c4 = *(const float4*)(c0p + (long)batch * 64 + T * 32 + q * 8 + hi * 4);
        hv[T][q * 4 + 0] = h4.x; hv[T][q * 4 + 1] = h4.y; hv[T][q * 4 + 2] = h4.z; hv[T][q * 4 + 3] = h4.w;
        cst[T][q * 4 + 0] = c4.x; cst[T][q * 4 + 1] = c4.y; cst[T][q * 4 + 2] = c4.z; cst[T][q * 4 + 3] = c4.w;
      }
    }
#pragma unroll
    for (int T = 0; T < 2; ++T)
#pragma unroll
      for (int j = 0; j < 8; ++j)
        hpk[T][j] = pk2(hv[T][2 * j], hv[T][2 * j + 1]);
    build_hfrag(hpk, hfrag);
  }
  {
    const float tx = traj_rel[(long)batch * 2 + 0];
    const float ty = traj_rel[(long)batch * 2 + 1];
    unsigned xpk[4];
#pragma unroll
    for (int j = 0; j < 4; ++j) {
      float vv[2];
#pragma unroll
      for (int u = 0; u < 2; ++u) {
        const int r = 2 * j + u;
        const int row = (r & 3) + ((r >> 2) << 3) + hi * 4;
        const float a0 = W_se[row * 6 + 0] + W_se[row * 6 + 2] + W_se[row * 6 + 4];
        const float a1 = W_se[row * 6 + 1] + W_se[row * 6 + 3] + W_se[row * 6 + 5];
        const float v = tx * a0 + ty * a1 + b_se[row];
        vv[u] = (v >= 0.f) ? v : 0.01f * v;
      }
      xpk[j] = pk2(vv[0], vv[1]);
    }
    xfrag = build_xfrag(xpk);
  }

  float* outP = out + (long)batch * 180;
  float* outC = out + (long)btot * 180 + (long)batch * 3;

  // ---------------- 30-step recurrence ----------------
#pragma unroll 1
  for (int t = 0; t < 30; ++t) {
    // Phase A: i/f/g gate MFMA chains TOGETHER (3 independent chains -> the
    // scheduler interleaves them, ~3x less exposed chain latency).
    // Phase B: all elementwise (48 exp2 + paired-rcp c' algebra).
    // Then o-chain + o-elementwise (keeps peak at 3 acc tiles, as R9).
    //   c' = (c*(1+ei)(1+eg) + (eg-1)(1+ef)) * rcp((1+ei)(1+eg)(1+ef))
    //   h  = (ec-1) * rcp((1+eo)(1+ec)),  ec = 2^(2*log2e*c')
#pragma unroll
    for (int T = 0; T < 2; ++T) {
      f32x16 ai = gate_acc(s_frag, 0 + T, lane, hfrag, xfrag,
                           load16(s_gb + hi * 128 + (0 + T) * 16));
      f32x16 af = gate_acc(s_frag, 2 + T, lane, hfrag, xfrag,
                           load16(s_gb + hi * 128 + (2 + T) * 16));
      f32x16 ag = gate_acc(s_frag, 4 + T, lane, hfrag, xfrag,
                           load16(s_gb + hi * 128 + (4 + T) * 16));
      FENCE();
#pragma unroll
      for (int r = 0; r < 16; ++r) {
        ai[r] = __builtin_amdgcn_exp2f(ai[r]);   // ei
        af[r] = __builtin_amdgcn_exp2f(af[r]);   // ef
        ag[r] = __builtin_amdgcn_exp2f(ag[r]);   // eg
      }
#pragma unroll
      for (int j = 0; j < 8; ++j) {
        const int r0 = 2 * j, r1 = 2 * j + 1;
        f32x2 A; A[0] = 1.0f + ai[r0]; A[1] = 1.0f + ai[r1];
        f32x2 B; B[0] = 1.0f + ag[r0]; B[1] = 1.0f + ag[r1];
        f32x2 F; F[0] = 1.0f + af[r0]; F[1] = 1.0f + af[r1];
        f32x2 G; G[0] = ag[r0] - 1.0f; G[1] = ag[r1] - 1.0f;
        f32x2 C; C[0] = cst[T][r0];    C[1] = cst[T][r1];
        const f32x2 AB = A * B;
        const f32x2 D  = AB * F;
        const f32x2 N  = C * AB + G * F;
        const float RP = __builtin_amdgcn_rcpf(D[0] * D[1]);
        cst[T][r0] = N[0] * (RP * D[1]);
        cst[T][r1] = N[1] * (RP * D[0]);
      }
      FENCE();
      {
        f32x16 ao = gate_acc(s_frag, 6 + T, lane, hfrag, xfrag,
                             load16(s_gb + hi * 128 + (6 + T) * 16));
#pragma unroll
        for (int j = 0; j < 8; ++j) {
          const int r0 = 2 * j, r1 = 2 * j + 1;
          f32x2 EC; EC[0] = __builtin_amdgcn_exp2f((2.0f * LOG2E) * cst[T][r0]);
                    EC[1] = __builtin_amdgcn_exp2f((2.0f * LOG2E) * cst[T][r1]);
          f32x2 O; O[0] = 1.0f + __builtin_amdgcn_exp2f(ao[r0]);
                   O[1] = 1.0f + __builtin_amdgcn_exp2f(ao[r1]);
          const f32x2 E1 = 1.0f + EC;
          const f32x2 D  = O * E1;
          const float RP = __builtin_amdgcn_rcpf(D[0] * D[1]);
          const float h0v = (EC[0] - 1.0f) * (RP * D[1]);
          const float h1v = (EC[1] - 1.0f) * (RP * D[0]);
          hpk[T][j] = pk2(h0v, h1v);
        }
      }
      FENCE();
    }
    build_hfrag(hpk, hfrag);

    // rel = h @ W_h2p^T + b_h2p (rows 0-5 of rel^T tile)
    f32x16 racc = load16(s_rb + hi * 16);
#pragma unroll
    for (int ks = 0; ks < 4; ++ks)
      racc = mfma_bf16(frag_of(s_frag[(40 + ks) * 64 + lane]), hfrag[ks], racc);

    // pred store
    if (USE_WS) {
      // coalesced staging layout matching final flat order: ws[(s*30+t)*btot + batch][2]
      if (hi == 0) {
        float2 v0; v0.x = racc[0]; v0.y = racc[1];
        float2 v1; v1.x = racc[2]; v1.y = racc[3];
        *(float2*)(wsP + ((long)(0 * 30 + t) * btot + batch) * 2) = v0;
        *(float2*)(wsP + ((long)(1 * 30 + t) * btot + batch) * 2) = v1;
      } else {
        float2 v2; v2.x = racc[0]; v2.y = racc[1];
        *(float2*)(wsP + ((long)(2 * 30 + t) * btot + batch) * 2) = v2;
      }
    } else {
      if (hi == 0) {
        float2 v0; v0.x = racc[0]; v0.y = racc[1];
        float2 v1; v1.x = racc[2]; v1.y = racc[3];
        *(float2*)(outP + t * 2)       = v0;
        *(float2*)(outP + 60 + t * 2)  = v1;
      } else {
        float2 v2; v2.x = racc[0]; v2.y = racc[1];
        *(float2*)(outP + 120 + t * 2) = v2;
      }
    }

    // x = leaky(rel @ W_se^T + b_se)
    {
      const unsigned qw = pk2(racc[0], racc[1]);
      const unsigned pw = pk2(racc[2], racc[3]); // upper lanes: rows 6,7 == 0
      uintv2 sw = __builtin_amdgcn_permlane32_swap(qw, 0u, false, false);
      uint4 rw; rw.x = sw[0]; rw.y = pw; rw.z = sw[1]; rw.w = 0u;
      f32x16 xacc = load16(s_xb + hi * 16);
      xacc = mfma_bf16(frag_of(s_frag[44 * 64 + lane]), frag_of(rw), xacc);
      unsigned xpk[4];
#pragma unroll
      for (int j = 0; j < 4; ++j) {
        float v0 = xacc[2 * j], v1 = xacc[2 * j + 1];
        v0 = (v0 >= 0.f) ? v0 : 0.01f * v0;
        v1 = (v1 >= 0.f) ? v1 : 0.01f * v1;
        xpk[j] = pk2(v0, v1);
      }
      xfrag = build_xfrag(xpk);
    }
  }

  // ---------------- conf = softmax(h @ W_conf^T + b_conf) ----------------
  {
    f32x16 cacc = load16(s_cb + hi * 16);
#pragma unroll
    for (int ks = 0; ks < 4; ++ks)
      cacc = mfma_bf16(frag_of(s_frag[(45 + ks) * 64 + lane]), hfrag[ks], cacc);
    if (hi == 0) {
      const float a = cacc[0], b = cacc[1], c = cacc[2];
      const float mx = fmaxf(a, fmaxf(b, c));
      const float e0 = __builtin_amdgcn_exp2f(LOG2E * (a - mx));
      const float e1 = __builtin_amdgcn_exp2f(LOG2E * (b - mx));
      const float e2 = __builtin_amdgcn_exp2f(LOG2E * (c - mx));
      const float rs = __builtin_amdgcn_rcpf(e0 + e1 + e2);
      outC[0] = e0 * rs; outC[1] = e1 * rs; outC[2] = e2 * rs;
    }
  }
}

// Copy ws[(s*30+t)][b][2] -> out[b][s*60+t*2+c]; LDS flat order == output flat order.
__global__ __launch_bounds__(256)
void transpose_pred(const float* __restrict__ ws, float* __restrict__ out, int btot)
{
  __shared__ float s_t[64][188];   // 188 pad: 752B row stride (16B-aligned, bank-spread)
  const int tid = threadIdx.x;
  const long b0 = (long)blockIdx.x * 64;

  // load: 90 (s,t) chunks x 64 batches of float2, coalesced on batch
#pragma unroll 1
  for (int i = 0; i < 23; ++i) {
    const int idx = tid + i * 256;
    if (idx < 5760) {
      const int e = idx >> 6, bb = idx & 63;
      const float2 v = *(const float2*)(ws + ((long)e * btot + b0 + bb) * 2);
      *(float2*)&s_t[bb][e * 2] = v;
    }
  }
  __syncthreads();

  // store: per batch 180 contiguous floats (720B), float4 granularity
#pragma unroll 1
  for (int i = 0; i < 12; ++i) {
    const int idx = tid + i * 256;
    if (idx < 2880) {
      const int b = idx / 45, k = idx % 45;
      *(float4*)(out + (b0 + b) * 180 + k * 4) = *(const float4*)&s_t[b][k * 4];
    }
  }
}

extern "C" void kernel_launch(void* const* d_in, const int* in_sizes, int n_in,
                              void* d_out, int out_size, void* d_ws, size_t ws_size,
                              hipStream_t stream) {
  const float* traj_rel = (const float*)d_in[1];
  const float* h0p    = (const float*)d_in[2];
  const float* c0p    = (const float*)d_in[3];
  const float* W_ih   = (const float*)d_in[4];
  const float* W_hh   = (const float*)d_in[5];
  const float* b_ih   = (const float*)d_in[6];
  const float* b_hh   = (const float*)d_in[7];
  const float* W_se   = (const float*)d_in[8];
  const float* b_se   = (const float*)d_in[9];
  const float* W_h2p  = (const float*)d_in[10];
  const float* b_h2p  = (const float*)d_in[11];
  const float* W_conf = (const float*)d_in[12];
  const float* b_conf = (const float*)d_in[13];

  const int btot = in_sizes[1] / 2;        // 131072
  const int grid = btot / 512;             // 16 waves/block * 32 batch/wave = 256 blocks

  const size_t ws_need = (size_t)90 * (size_t)btot * 2 * sizeof(float);
  if (ws_size >= ws_need) {
    mmdec_kernel<true><<<grid, 1024, 0, stream>>>(traj_rel, h0p, c0p, W_ih, W_hh, b_ih, b_hh,
                                                  W_se, b_se, W_h2p, b_h2p, W_conf, b_conf,
                                                  (float*)d_out, (float*)d_ws, btot);
    transpose_pred<<<btot / 64, 256, 0, stream>>>((const float*)d_ws, (float*)d_out, btot);
  } else {
    mmdec_kernel<false><<<grid, 1024, 0, stream>>>(traj_rel, h0p, c0p, W_ih, W_hh, b_ih, b_hh,
                                                   W_se, b_se, W_h2p, b_h2p, W_conf, b_conf,
                                                   (float*)d_out, nullptr, btot);
  }
}